// Round 2
// baseline (872.804 us; speedup 1.0000x reference)
//
#include <hip/hip_runtime.h>
#include <hip/hip_bf16.h>

typedef unsigned short u16;
typedef unsigned int u32;
typedef u16 u16x8 __attribute__((ext_vector_type(8)));
typedef float f32x4 __attribute__((ext_vector_type(4)));

__device__ __forceinline__ u16 f2bf(float f) {
  union { float f; u32 u; } v; v.f = f;
  u32 r = v.u + 0x7FFFu + ((v.u >> 16) & 1u);
  return (u16)(r >> 16);
}
__device__ __forceinline__ float bf2f(u16 h) {
  union { u32 u; float f; } v; v.u = ((u32)h) << 16;
  return v.f;
}
__device__ __forceinline__ void mfma_bf16_16x16x32(f32x4& acc, const f32x4& a, const f32x4& b) {
  asm("v_mfma_f32_16x16x32_bf16 %0, %1, %2, %0" : "+v"(acc) : "v"(a), "v"(b));
}
__device__ __forceinline__ void gload_lds16(const void* g, void* l) {
  __builtin_amdgcn_global_load_lds(
      (const __attribute__((address_space(1))) unsigned int*)g,
      (__attribute__((address_space(3))) unsigned int*)l, 16, 0, 0);
}

// ---------------- fp32 -> bf16 weight convert ----------------
__global__ __launch_bounds__(256) void cvt_k(const float* __restrict__ src,
                                             u16* __restrict__ dst, int n8) {
  int i = blockIdx.x * 256 + threadIdx.x;
  if (i >= n8) return;
  float4 f0 = *(const float4*)&src[(size_t)i * 8];
  float4 f1 = *(const float4*)&src[(size_t)i * 8 + 4];
  u16x8 o;
  o[0] = f2bf(f0.x); o[1] = f2bf(f0.y); o[2] = f2bf(f0.z); o[3] = f2bf(f0.w);
  o[4] = f2bf(f1.x); o[5] = f2bf(f1.y); o[6] = f2bf(f1.z); o[7] = f2bf(f1.w);
  *(u16x8*)&dst[(size_t)i * 8] = o;
}

// ---------------- RMSNorm (fp32 in, bf16 out) ----------------
__global__ __launch_bounds__(256) void rmsnorm_k(const float* __restrict__ X,
                                                 const float* __restrict__ W,
                                                 u16* __restrict__ O) {
  const int row = blockIdx.x;
  const int tid = threadIdx.x;
  const float* x = X + (size_t)row * 2048;
  float4 v0 = *(const float4*)&x[tid * 8];
  float4 v1 = *(const float4*)&x[tid * 8 + 4];
  float s = v0.x * v0.x + v0.y * v0.y + v0.z * v0.z + v0.w * v0.w
          + v1.x * v1.x + v1.y * v1.y + v1.z * v1.z + v1.w * v1.w;
  #pragma unroll
  for (int m = 1; m < 64; m <<= 1) s += __shfl_xor(s, m);
  __shared__ float red[4];
  if ((tid & 63) == 0) red[tid >> 6] = s;
  __syncthreads();
  float tot = red[0] + red[1] + red[2] + red[3];
  float r = rsqrtf(tot * (1.0f / 2048.0f) + 1e-6f);
  float4 w0 = *(const float4*)&W[tid * 8];
  float4 w1 = *(const float4*)&W[tid * 8 + 4];
  u16x8 o;
  o[0] = f2bf(v0.x * r * w0.x); o[1] = f2bf(v0.y * r * w0.y);
  o[2] = f2bf(v0.z * r * w0.z); o[3] = f2bf(v0.w * r * w0.w);
  o[4] = f2bf(v1.x * r * w1.x); o[5] = f2bf(v1.y * r * w1.y);
  o[6] = f2bf(v1.z * r * w1.z); o[7] = f2bf(v1.w * r * w1.w);
  *(u16x8*)&O[(size_t)row * 2048 + tid * 8] = o;
}

// ---------------- GEMM: C[M,N] = A[M,K] * B[N,K]^T  (bf16 in, epilogues) ---
// m97 structure: 128x128 tile, BK=32, global_load_lds width-16 staging.
#define EPI_F32 0
#define EPI_ADDF32 1
#define EPI_BF16 2
#define EPI_SILUMUL 3

template <int EPI>
__global__ __launch_bounds__(256) void gemm_bt(const u16* __restrict__ A,
                                               const u16* __restrict__ B,
                                               float* __restrict__ Cf,
                                               u16* __restrict__ Cb,
                                               const float* __restrict__ R,
                                               const u16* __restrict__ G1,
                                               int M, int N, int K) {
  __shared__ __align__(16) u16 As[128 * 32];
  __shared__ __align__(16) u16 Bs[128 * 32];
  const int tid = threadIdx.x;
  const int lane = tid & 63;
  const int w = tid >> 6;
  const int wm = w >> 1, wn = w & 1;
  const int m0 = blockIdx.y * 128, n0 = blockIdx.x * 128;
  const int r0 = tid >> 2;
  const int c0 = (tid & 3) * 8;
  const int r1 = r0 + 64;
  const int laneM = lane & 15;
  const int laneK = (lane >> 4) * 8;

  f32x4 acc[4][4];
  #pragma unroll
  for (int i = 0; i < 4; i++)
    #pragma unroll
    for (int j = 0; j < 4; j++) acc[i][j] = (f32x4){0.f, 0.f, 0.f, 0.f};

  const u16* Ar0 = &A[(size_t)(m0 + r0) * K + c0];
  const u16* Ar1 = &A[(size_t)(m0 + r1) * K + c0];
  const u16* Br0 = &B[(size_t)(n0 + r0) * K + c0];
  const u16* Br1 = &B[(size_t)(n0 + r1) * K + c0];
  u16* lA0 = &As[r0 * 32 + c0];
  u16* lA1 = &As[r1 * 32 + c0];
  u16* lB0 = &Bs[r0 * 32 + c0];
  u16* lB1 = &Bs[r1 * 32 + c0];

  for (int kt = 0; kt < K; kt += 32) {
    __syncthreads();   // previous tile's reads complete before overwrite
    gload_lds16(Ar0 + kt, lA0);
    gload_lds16(Ar1 + kt, lA1);
    gload_lds16(Br0 + kt, lB0);
    gload_lds16(Br1 + kt, lB1);
    __syncthreads();   // drains vmcnt: LDS tile ready
    f32x4 af[4], bfr[4];
    #pragma unroll
    for (int mi = 0; mi < 4; mi++)
      af[mi] = *(const f32x4*)&As[(wm * 64 + mi * 16 + laneM) * 32 + laneK];
    #pragma unroll
    for (int ni = 0; ni < 4; ni++)
      bfr[ni] = *(const f32x4*)&Bs[(wn * 64 + ni * 16 + laneM) * 32 + laneK];
    #pragma unroll
    for (int mi = 0; mi < 4; mi++)
      #pragma unroll
      for (int ni = 0; ni < 4; ni++)
        mfma_bf16_16x16x32(acc[mi][ni], af[mi], bfr[ni]);
  }

  const int rowb = (lane >> 4) * 4;
  const int coll = lane & 15;
  #pragma unroll
  for (int mi = 0; mi < 4; mi++) {
    #pragma unroll
    for (int ni = 0; ni < 4; ni++) {
      #pragma unroll
      for (int i = 0; i < 4; i++) {
        int row = m0 + wm * 64 + mi * 16 + rowb + i;
        int col = n0 + wn * 64 + ni * 16 + coll;
        size_t idx = (size_t)row * N + col;
        float v = acc[mi][ni][i];
        if constexpr (EPI == EPI_F32) {
          Cf[idx] = v;
        } else if constexpr (EPI == EPI_ADDF32) {
          Cf[idx] = v + R[idx];
        } else if constexpr (EPI == EPI_BF16) {
          Cb[idx] = f2bf(v);
        } else {
          float g = bf2f(G1[idx]);
          float sg = g / (1.0f + __expf(-g));
          Cb[idx] = f2bf(sg * v);
        }
      }
    }
  }
}

// ---------------- RoPE + Qe/Ke build + V transpose ----------------
__device__ __forceinline__ void rope_row(const float* __restrict__ src,
                                         u16* __restrict__ dst, int s, int q4) {
  float vv[32];
  #pragma unroll
  for (int t = 0; t < 8; t++) {
    float4 f = *(const float4*)&src[t * 4];
    vv[t * 4] = f.x; vv[t * 4 + 1] = f.y; vv[t * 4 + 2] = f.z; vv[t * 4 + 3] = f.w;
  }
  u16 o1[32], o2[32];
  #pragma unroll
  for (int jl = 0; jl < 16; jl++) {
    int j = q4 * 16 + jl;
    float inv = exp2f(-(float)j * 0.20762050593046014f); // log2(10000)/64
    float ang = (float)s * inv;
    float sn, cs;
    __sincosf(ang, &sn, &cs);
    float a = vv[2 * jl], b = vv[2 * jl + 1];
    float r1 = a * cs - b * sn;
    float r2 = a * sn + b * cs;
    o1[2 * jl] = f2bf(r1);
    o1[2 * jl + 1] = f2bf(r2);
    o2[2 * jl] = f2bf(0.31622776601683794f * r1 * r1);  // sqrt(LAM)*q^2
    o2[2 * jl + 1] = f2bf(0.31622776601683794f * r2 * r2);
  }
  #pragma unroll
  for (int t = 0; t < 4; t++) {
    *(u16x8*)&dst[q4 * 32 + t * 8] = *(const u16x8*)&o1[t * 8];
    *(u16x8*)&dst[128 + q4 * 32 + t * 8] = *(const u16x8*)&o2[t * 8];
  }
}

__global__ __launch_bounds__(256) void qkv_post_k(const float* __restrict__ Qf,
                                                  const float* __restrict__ Kf,
                                                  const float* __restrict__ Vf,
                                                  u16* __restrict__ Qe,
                                                  u16* __restrict__ Ke,
                                                  u16* __restrict__ Vt) {
  const int st = blockIdx.x;  // 0..15
  const int bh = blockIdx.y;  // 0..31
  const int b = bh >> 4, h = bh & 15;
  const int tid = threadIdx.x;
  {
    int r = tid >> 2, q4 = tid & 3;
    int s = st * 64 + r;
    size_t rowin = ((size_t)b * 1024 + s) * 2048 + h * 128 + q4 * 32;
    size_t rowe = ((size_t)bh * 1024 + s) * 256;
    rope_row(Qf + rowin, Qe + rowe, s, q4);
    rope_row(Kf + rowin, Ke + rowe, s, q4);
  }
  __shared__ __align__(16) u16 vts[128 * 72];
  {
    int r = tid >> 2, q4 = tid & 3;
    int s = st * 64 + r;
    const float* src = Vf + ((size_t)b * 1024 + s) * 2048 + h * 128 + q4 * 32;
    #pragma unroll
    for (int k = 0; k < 32; k += 4) {
      float4 f = *(const float4*)&src[k];
      int d = q4 * 32 + k;
      vts[(d + 0) * 72 + r] = f2bf(f.x);
      vts[(d + 1) * 72 + r] = f2bf(f.y);
      vts[(d + 2) * 72 + r] = f2bf(f.z);
      vts[(d + 3) * 72 + r] = f2bf(f.w);
    }
  }
  __syncthreads();
  {
    int d = tid >> 1, sp = (tid & 1) * 32;
    u16* dst = Vt + ((size_t)bh * 128 + d) * 1024 + st * 64 + sp;
    #pragma unroll
    for (int k = 0; k < 32; k += 8)
      *(u16x8*)&dst[k] = *(const u16x8*)&vts[d * 72 + sp + k];
  }
}

// ---------------- Flash attention, split-K 4-way ----------------
// Block = 4 waves, 16 q-rows. Wave w handles kt tiles [w*4, w*4+4) with
// private (m,l,accO); 2-stage LDS merge tree at the end.
__global__ __launch_bounds__(256) void attn_k(const u16* __restrict__ Qe,
                                              const u16* __restrict__ Ke,
                                              const u16* __restrict__ Vt,
                                              u16* __restrict__ AO) {
  const int qt = blockIdx.x;  // 0..63 (16 rows each)
  const int bh = blockIdx.y;  // 0..31
  const int b = bh >> 4, h = bh & 15;
  const int tid = threadIdx.x;
  const int w = tid >> 6, lane = tid & 63;
  const int laneM = lane & 15, laneG = lane >> 4;
  __shared__ __align__(16) u16 P_lds[4 * 1024];
  __shared__ __align__(16) float OB[2][16 * 128];
  __shared__ float MB[2][16], LB[2][16];
  u16* pl = &P_lds[w * 1024];

  const size_t qbase = ((size_t)bh * 1024 + qt * 16 + laneM) * 256 + laneG * 8;
  f32x4 qf[8];
  #pragma unroll
  for (int kk = 0; kk < 8; kk++) qf[kk] = *(const f32x4*)&Qe[qbase + kk * 32];

  float m_i[4], l_i[4];
  #pragma unroll
  for (int i = 0; i < 4; i++) { m_i[i] = -1e30f; l_i[i] = 0.f; }
  f32x4 accO[8];
  #pragma unroll
  for (int n = 0; n < 8; n++) accO[n] = (f32x4){0.f, 0.f, 0.f, 0.f};

  const float scale = 0.08838834764831845f;  // 1/sqrt(128)
  const size_t kebase = (size_t)bh * 1024 * 256;
  const size_t vtbase = (size_t)bh * 128 * 1024;

  for (int kt = w * 4; kt < w * 4 + 4; kt++) {
    f32x4 accS[4];
    #pragma unroll
    for (int n = 0; n < 4; n++) accS[n] = (f32x4){0.f, 0.f, 0.f, 0.f};
    #pragma unroll
    for (int n = 0; n < 4; n++) {
      size_t kb = kebase + ((size_t)(kt * 64 + n * 16 + laneM)) * 256 + laneG * 8;
      #pragma unroll
      for (int kk = 0; kk < 8; kk++) {
        f32x4 kf = *(const f32x4*)&Ke[kb + kk * 32];
        mfma_bf16_16x16x32(accS[n], qf[kk], kf);
      }
    }
    float p[4][4];  // [n][i]
    float sf[4];
    #pragma unroll
    for (int i = 0; i < 4; i++) {
      float mx = fmaxf(fmaxf(accS[0][i], accS[1][i]), fmaxf(accS[2][i], accS[3][i]));
      mx *= scale;
      #pragma unroll
      for (int m = 1; m < 16; m <<= 1) mx = fmaxf(mx, __shfl_xor(mx, m));
      float mnew = fmaxf(m_i[i], mx);
      sf[i] = __expf(m_i[i] - mnew);
      m_i[i] = mnew;
      float rs = 0.f;
      #pragma unroll
      for (int n = 0; n < 4; n++) {
        float pv = __expf(accS[n][i] * scale - mnew);
        p[n][i] = pv;
        rs += pv;
      }
      #pragma unroll
      for (int m = 1; m < 16; m <<= 1) rs += __shfl_xor(rs, m);
      l_i[i] = l_i[i] * sf[i] + rs;
    }
    #pragma unroll
    for (int n = 0; n < 8; n++) {
      accO[n][0] *= sf[0]; accO[n][1] *= sf[1];
      accO[n][2] *= sf[2]; accO[n][3] *= sf[3];
    }
    #pragma unroll
    for (int n = 0; n < 4; n++)
      #pragma unroll
      for (int i = 0; i < 4; i++) {
        int row = laneG * 4 + i;
        int col = n * 16 + laneM;
        pl[row * 64 + (col ^ (((row >> 2) & 3) << 4))] = f2bf(p[n][i]);
      }
    f32x4 pa[2];
    #pragma unroll
    for (int kk = 0; kk < 2; kk++) {
      int row = laneM;
      int c0 = kk * 32 + laneG * 8;
      pa[kk] = *(const f32x4*)&pl[row * 64 + (c0 ^ (((row >> 2) & 3) << 4))];
    }
    #pragma unroll
    for (int n = 0; n < 8; n++) {
      size_t vb = vtbase + ((size_t)(n * 16 + laneM)) * 1024 + kt * 64 + laneG * 8;
      f32x4 v0 = *(const f32x4*)&Vt[vb];
      f32x4 v1 = *(const f32x4*)&Vt[vb + 32];
      mfma_bf16_16x16x32(accO[n], pa[0], v0);
      mfma_bf16_16x16x32(accO[n], pa[1], v1);
    }
  }

  // ---- 2-stage split-K merge: (w1->w0), (w3->w2), then (w2->w0) ----
  __syncthreads();
  const int pair = w >> 1;
  if (w & 1) {  // w1 -> OB[0], w3 -> OB[1]
    #pragma unroll
    for (int n = 0; n < 8; n++)
      #pragma unroll
      for (int i = 0; i < 4; i++)
        OB[pair][(laneG * 4 + i) * 128 + n * 16 + laneM] = accO[n][i];
    if (laneM == 0)
      #pragma unroll
      for (int i = 0; i < 4; i++) {
        MB[pair][laneG * 4 + i] = m_i[i];
        LB[pair][laneG * 4 + i] = l_i[i];
      }
  }
  __syncthreads();
  if (!(w & 1)) {
    #pragma unroll
    for (int i = 0; i < 4; i++) {
      float m1 = MB[pair][laneG * 4 + i];
      float l1 = LB[pair][laneG * 4 + i];
      float M = fmaxf(m_i[i], m1);
      float a = __expf(m_i[i] - M);
      float bm = __expf(m1 - M);
      #pragma unroll
      for (int n = 0; n < 8; n++)
        accO[n][i] = accO[n][i] * a + OB[pair][(laneG * 4 + i) * 128 + n * 16 + laneM] * bm;
      l_i[i] = l_i[i] * a + l1 * bm;
      m_i[i] = M;
    }
  }
  __syncthreads();
  if (w == 2) {
    #pragma unroll
    for (int n = 0; n < 8; n++)
      #pragma unroll
      for (int i = 0; i < 4; i++)
        OB[1][(laneG * 4 + i) * 128 + n * 16 + laneM] = accO[n][i];
    if (laneM == 0)
      #pragma unroll
      for (int i = 0; i < 4; i++) {
        MB[1][laneG * 4 + i] = m_i[i];
        LB[1][laneG * 4 + i] = l_i[i];
      }
  }
  __syncthreads();
  if (w == 0) {
    #pragma unroll
    for (int i = 0; i < 4; i++) {
      float m1 = MB[1][laneG * 4 + i];
      float l1 = LB[1][laneG * 4 + i];
      float M = fmaxf(m_i[i], m1);
      float a = __expf(m_i[i] - M);
      float bm = __expf(m1 - M);
      #pragma unroll
      for (int n = 0; n < 8; n++)
        accO[n][i] = accO[n][i] * a + OB[1][(laneG * 4 + i) * 128 + n * 16 + laneM] * bm;
      l_i[i] = l_i[i] * a + l1 * bm;
    }
    #pragma unroll
    for (int i = 0; i < 4; i++) {
      float inv_l = 1.f / l_i[i];
      int row = b * 1024 + qt * 16 + laneG * 4 + i;
      #pragma unroll
      for (int n = 0; n < 8; n++) {
        float o = accO[n][i] * inv_l;
        o = o + 0.05f * o * o;  // gate collapses (out2==out1); HAD term
        AO[(size_t)row * 2048 + h * 128 + n * 16 + laneM] = f2bf(o);
      }
    }
  }
}

// ---------------- launch ----------------
extern "C" void kernel_launch(void* const* d_in, const int* in_sizes, int n_in,
                              void* d_out, int out_size, void* d_ws, size_t ws_size,
                              hipStream_t stream) {
  const float* x   = (const float*)d_in[0];
  const float* n1w = (const float*)d_in[1];
  const float* n2w = (const float*)d_in[2];
  const float* wq  = (const float*)d_in[3];
  const float* wk  = (const float*)d_in[4];
  const float* wv  = (const float*)d_in[5];
  const float* wo  = (const float*)d_in[6];
  const float* w1  = (const float*)d_in[8];
  const float* w3  = (const float*)d_in[9];
  const float* w2  = (const float*)d_in[10];

  char* ws = (char*)d_ws;
  u16* WQb = (u16*)(ws + 0);
  u16* WKb = (u16*)(ws + 8388608);
  u16* WVb = (u16*)(ws + 16777216);
  u16* WOb = (u16*)(ws + 25165824);
  u16* W1b = (u16*)(ws + 33554432);
  u16* W3b = (u16*)(ws + 67108864);
  u16* W2b = (u16*)(ws + 100663296);
  u16* XN  = (u16*)(ws + 134217728);
  float* QF = (float*)(ws + 142606336);
  float* KF = (float*)(ws + 159383552);
  float* VF = (float*)(ws + 176160768);
  u16* G1  = (u16*)(ws + 142606336);   // reuse QF/KF after qkv_post
  u16* QE  = (u16*)(ws + 192937984);
  u16* KE  = (u16*)(ws + 209715200);
  u16* U   = (u16*)(ws + 192937984);   // reuse QE/KE after attention
  u16* VT  = (u16*)(ws + 226492416);
  u16* AO  = (u16*)(ws + 234881024);
  float* H = (float*)(ws + 243269632);

  cvt_k<<<2048, 256, 0, stream>>>(wq, WQb, 524288);
  cvt_k<<<2048, 256, 0, stream>>>(wk, WKb, 524288);
  cvt_k<<<2048, 256, 0, stream>>>(wv, WVb, 524288);
  cvt_k<<<2048, 256, 0, stream>>>(wo, WOb, 524288);
  cvt_k<<<8192, 256, 0, stream>>>(w1, W1b, 2097152);
  cvt_k<<<8192, 256, 0, stream>>>(w3, W3b, 2097152);
  cvt_k<<<8192, 256, 0, stream>>>(w2, W2b, 2097152);

  rmsnorm_k<<<2048, 256, 0, stream>>>(x, n1w, XN);

  gemm_bt<EPI_F32><<<dim3(16, 16), 256, 0, stream>>>(XN, WQb, QF, nullptr, nullptr, nullptr, 2048, 2048, 2048);
  gemm_bt<EPI_F32><<<dim3(16, 16), 256, 0, stream>>>(XN, WKb, KF, nullptr, nullptr, nullptr, 2048, 2048, 2048);
  gemm_bt<EPI_F32><<<dim3(16, 16), 256, 0, stream>>>(XN, WVb, VF, nullptr, nullptr, nullptr, 2048, 2048, 2048);

  qkv_post_k<<<dim3(16, 32), 256, 0, stream>>>(QF, KF, VF, QE, KE, VT);

  attn_k<<<dim3(64, 32), 256, 0, stream>>>(QE, KE, VT, AO);

  gemm_bt<EPI_ADDF32><<<dim3(16, 16), 256, 0, stream>>>(AO, WOb, H, nullptr, x, nullptr, 2048, 2048, 2048);

  rmsnorm_k<<<2048, 256, 0, stream>>>(H, n2w, XN);

  gemm_bt<EPI_BF16><<<dim3(64, 16), 256, 0, stream>>>(XN, W1b, nullptr, G1, nullptr, nullptr, 2048, 8192, 2048);
  gemm_bt<EPI_SILUMUL><<<dim3(64, 16), 256, 0, stream>>>(XN, W3b, nullptr, U, nullptr, G1, 2048, 8192, 2048);
  gemm_bt<EPI_ADDF32><<<dim3(16, 16), 256, 0, stream>>>(U, W2b, (float*)d_out, nullptr, H, nullptr, 2048, 2048, 8192);
}

// Round 5
// 730.287 us; speedup vs baseline: 1.1952x; 1.1952x over previous
//
#include <hip/hip_runtime.h>
#include <hip/hip_bf16.h>

typedef unsigned short u16;
typedef unsigned int u32;
typedef u16 u16x8 __attribute__((ext_vector_type(8)));
typedef float f32x4 __attribute__((ext_vector_type(4)));

__device__ __forceinline__ u16 f2bf(float f) {
  union { float f; u32 u; } v; v.f = f;
  u32 r = v.u + 0x7FFFu + ((v.u >> 16) & 1u);
  return (u16)(r >> 16);
}
__device__ __forceinline__ float bf2f(u16 h) {
  union { u32 u; float f; } v; v.u = ((u32)h) << 16;
  return v.f;
}
__device__ __forceinline__ void mfma_bf16_16x16x32(f32x4& acc, const f32x4& a, const f32x4& b) {
  asm("v_mfma_f32_16x16x32_bf16 %0, %1, %2, %0" : "+v"(acc) : "v"(a), "v"(b));
}
__device__ __forceinline__ void gload_lds16(const void* g, void* l) {
  __builtin_amdgcn_global_load_lds(
      (const __attribute__((address_space(1))) unsigned int*)g,
      (__attribute__((address_space(3))) unsigned int*)l, 16, 0, 0);
}

// ---------------- fp32 -> bf16 weight convert ----------------
__global__ __launch_bounds__(256) void cvt_k(const float* __restrict__ src,
                                             u16* __restrict__ dst, int n8) {
  int i = blockIdx.x * 256 + threadIdx.x;
  if (i >= n8) return;
  float4 f0 = *(const float4*)&src[(size_t)i * 8];
  float4 f1 = *(const float4*)&src[(size_t)i * 8 + 4];
  u16x8 o;
  o[0] = f2bf(f0.x); o[1] = f2bf(f0.y); o[2] = f2bf(f0.z); o[3] = f2bf(f0.w);
  o[4] = f2bf(f1.x); o[5] = f2bf(f1.y); o[6] = f2bf(f1.z); o[7] = f2bf(f1.w);
  *(u16x8*)&dst[(size_t)i * 8] = o;
}

// ---------------- RMSNorm (fp32 in, bf16 out) ----------------
__global__ __launch_bounds__(256) void rmsnorm_k(const float* __restrict__ X,
                                                 const float* __restrict__ W,
                                                 u16* __restrict__ O) {
  const int row = blockIdx.x;
  const int tid = threadIdx.x;
  const float* x = X + (size_t)row * 2048;
  float4 v0 = *(const float4*)&x[tid * 8];
  float4 v1 = *(const float4*)&x[tid * 8 + 4];
  float s = v0.x * v0.x + v0.y * v0.y + v0.z * v0.z + v0.w * v0.w
          + v1.x * v1.x + v1.y * v1.y + v1.z * v1.z + v1.w * v1.w;
  #pragma unroll
  for (int m = 1; m < 64; m <<= 1) s += __shfl_xor(s, m);
  __shared__ float red[4];
  if ((tid & 63) == 0) red[tid >> 6] = s;
  __syncthreads();
  float tot = red[0] + red[1] + red[2] + red[3];
  float r = rsqrtf(tot * (1.0f / 2048.0f) + 1e-6f);
  float4 w0 = *(const float4*)&W[tid * 8];
  float4 w1 = *(const float4*)&W[tid * 8 + 4];
  u16x8 o;
  o[0] = f2bf(v0.x * r * w0.x); o[1] = f2bf(v0.y * r * w0.y);
  o[2] = f2bf(v0.z * r * w0.z); o[3] = f2bf(v0.w * r * w0.w);
  o[4] = f2bf(v1.x * r * w1.x); o[5] = f2bf(v1.y * r * w1.y);
  o[6] = f2bf(v1.z * r * w1.z); o[7] = f2bf(v1.w * r * w1.w);
  *(u16x8*)&O[(size_t)row * 2048 + tid * 8] = o;
}

// ---------------- GEMM: C[M,N] = A[M,K] * B[N,K]^T  (bf16 in, epilogues) ---
#define EPI_F32 0
#define EPI_ADDF32 1
#define EPI_BF16 2
#define EPI_SILUMUL 3

template <int EPI>
__global__ __launch_bounds__(256) void gemm_bt(const u16* __restrict__ A,
                                               const u16* __restrict__ B,
                                               float* __restrict__ Cf,
                                               u16* __restrict__ Cb,
                                               const float* __restrict__ R,
                                               const u16* __restrict__ G1,
                                               int M, int N, int K) {
  __shared__ __align__(16) u16 As[128 * 32];
  __shared__ __align__(16) u16 Bs[128 * 32];
  const int tid = threadIdx.x;
  const int lane = tid & 63;
  const int w = tid >> 6;
  const int wm = w >> 1, wn = w & 1;
  const int m0 = blockIdx.y * 128, n0 = blockIdx.x * 128;
  const int r0 = tid >> 2;
  const int c0 = (tid & 3) * 8;
  const int r1 = r0 + 64;
  const int laneM = lane & 15;
  const int laneK = (lane >> 4) * 8;

  f32x4 acc[4][4];
  #pragma unroll
  for (int i = 0; i < 4; i++)
    #pragma unroll
    for (int j = 0; j < 4; j++) acc[i][j] = (f32x4){0.f, 0.f, 0.f, 0.f};

  const u16* Ar0 = &A[(size_t)(m0 + r0) * K + c0];
  const u16* Ar1 = &A[(size_t)(m0 + r1) * K + c0];
  const u16* Br0 = &B[(size_t)(n0 + r0) * K + c0];
  const u16* Br1 = &B[(size_t)(n0 + r1) * K + c0];
  u16* lA0 = &As[r0 * 32 + c0];
  u16* lA1 = &As[r1 * 32 + c0];
  u16* lB0 = &Bs[r0 * 32 + c0];
  u16* lB1 = &Bs[r1 * 32 + c0];

  for (int kt = 0; kt < K; kt += 32) {
    __syncthreads();
    gload_lds16(Ar0 + kt, lA0);
    gload_lds16(Ar1 + kt, lA1);
    gload_lds16(Br0 + kt, lB0);
    gload_lds16(Br1 + kt, lB1);
    __syncthreads();
    f32x4 af[4], bfr[4];
    #pragma unroll
    for (int mi = 0; mi < 4; mi++)
      af[mi] = *(const f32x4*)&As[(wm * 64 + mi * 16 + laneM) * 32 + laneK];
    #pragma unroll
    for (int ni = 0; ni < 4; ni++)
      bfr[ni] = *(const f32x4*)&Bs[(wn * 64 + ni * 16 + laneM) * 32 + laneK];
    #pragma unroll
    for (int mi = 0; mi < 4; mi++)
      #pragma unroll
      for (int ni = 0; ni < 4; ni++)
        mfma_bf16_16x16x32(acc[mi][ni], af[mi], bfr[ni]);
  }

  const int rowb = (lane >> 4) * 4;
  const int coll = lane & 15;
  #pragma unroll
  for (int mi = 0; mi < 4; mi++) {
    #pragma unroll
    for (int ni = 0; ni < 4; ni++) {
      #pragma unroll
      for (int i = 0; i < 4; i++) {
        int row = m0 + wm * 64 + mi * 16 + rowb + i;
        int col = n0 + wn * 64 + ni * 16 + coll;
        size_t idx = (size_t)row * N + col;
        float v = acc[mi][ni][i];
        if constexpr (EPI == EPI_F32) {
          Cf[idx] = v;
        } else if constexpr (EPI == EPI_ADDF32) {
          Cf[idx] = v + R[idx];
        } else if constexpr (EPI == EPI_BF16) {
          Cb[idx] = f2bf(v);
        } else {
          float g = bf2f(G1[idx]);
          float sg = g / (1.0f + __expf(-g));
          Cb[idx] = f2bf(sg * v);
        }
      }
    }
  }
}

// ---------------- RoPE + Qe/Ke build + V transpose ----------------
// Qe/Ke rows: [rope(x) | sqrt(LAM)*rope(x)^2]  (symmetric split, R1-verified)
__device__ __forceinline__ void rope_row(const float* __restrict__ src,
                                         u16* __restrict__ dst, int s, int q4) {
  float vv[32];
  #pragma unroll
  for (int t = 0; t < 8; t++) {
    float4 f = *(const float4*)&src[t * 4];
    vv[t * 4] = f.x; vv[t * 4 + 1] = f.y; vv[t * 4 + 2] = f.z; vv[t * 4 + 3] = f.w;
  }
  u16 o1[32], o2[32];
  #pragma unroll
  for (int jl = 0; jl < 16; jl++) {
    int j = q4 * 16 + jl;
    float inv = exp2f(-(float)j * 0.20762050593046014f); // log2(10000)/64
    float ang = (float)s * inv;
    float sn, cs;
    __sincosf(ang, &sn, &cs);
    float a = vv[2 * jl], b = vv[2 * jl + 1];
    float r1 = a * cs - b * sn;
    float r2 = a * sn + b * cs;
    o1[2 * jl] = f2bf(r1);
    o1[2 * jl + 1] = f2bf(r2);
    o2[2 * jl] = f2bf(0.31622776601683794f * r1 * r1);  // sqrt(LAM)*x^2
    o2[2 * jl + 1] = f2bf(0.31622776601683794f * r2 * r2);
  }
  #pragma unroll
  for (int t = 0; t < 4; t++) {
    *(u16x8*)&dst[q4 * 32 + t * 8] = *(const u16x8*)&o1[t * 8];
    *(u16x8*)&dst[128 + q4 * 32 + t * 8] = *(const u16x8*)&o2[t * 8];
  }
}

__global__ __launch_bounds__(256) void qkv_post_k(const float* __restrict__ Qf,
                                                  const float* __restrict__ Kf,
                                                  const float* __restrict__ Vf,
                                                  u16* __restrict__ Qe,
                                                  u16* __restrict__ Ke,
                                                  u16* __restrict__ Vt) {
  const int st = blockIdx.x;  // 0..15
  const int bh = blockIdx.y;  // 0..31
  const int b = bh >> 4, h = bh & 15;
  const int tid = threadIdx.x;
  {
    int r = tid >> 2, q4 = tid & 3;
    int s = st * 64 + r;
    size_t rowin = ((size_t)b * 1024 + s) * 2048 + h * 128 + q4 * 32;
    size_t rowe = ((size_t)bh * 1024 + s) * 256;
    rope_row(Qf + rowin, Qe + rowe, s, q4);
    rope_row(Kf + rowin, Ke + rowe, s, q4);
  }
  __shared__ __align__(16) u16 vts[128 * 72];
  {
    int r = tid >> 2, q4 = tid & 3;
    int s = st * 64 + r;
    const float* src = Vf + ((size_t)b * 1024 + s) * 2048 + h * 128 + q4 * 32;
    #pragma unroll
    for (int k = 0; k < 32; k += 4) {
      float4 f = *(const float4*)&src[k];
      int d = q4 * 32 + k;
      vts[(d + 0) * 72 + r] = f2bf(f.x);
      vts[(d + 1) * 72 + r] = f2bf(f.y);
      vts[(d + 2) * 72 + r] = f2bf(f.z);
      vts[(d + 3) * 72 + r] = f2bf(f.w);
    }
  }
  __syncthreads();
  {
    int d = tid >> 1, sp = (tid & 1) * 32;
    u16* dst = Vt + ((size_t)bh * 128 + d) * 1024 + st * 64 + sp;
    #pragma unroll
    for (int k = 0; k < 32; k += 8)
      *(u16x8*)&dst[k] = *(const u16x8*)&vts[d * 72 + sp + k];
  }
}

// ---------------- Flash attention: R1 math + LDS-staged K/V (reg-staged) --
// Block: 64 q rows (wave w owns rows qt*64+w*16..+16).  Grid (bh=32, qt=16).
// KV loop: 32 tiles of 32.  LDS: K dbuf 2x16KB [32][512B] swz (r&7)<<4;
// V dbuf 2x8KB [128][64B] swz ((r>>1)&3)<<4; P/wave [16][64]u16 (R1 swizzle).
// Staging: global->reg->swizzled ds_write (plain instructions, no DMA rules).
__global__ __launch_bounds__(256, 2) void attn_k(const u16* __restrict__ Qe,
                                                 const u16* __restrict__ Ke,
                                                 const u16* __restrict__ Vt,
                                                 u16* __restrict__ AO) {
  const int bh = blockIdx.x;  // 0..31
  const int qt = blockIdx.y;  // 0..15
  const int b = bh >> 4, h = bh & 15;
  const int tid = threadIdx.x;
  const int w = tid >> 6, lane = tid & 63;
  const int laneM = lane & 15, laneG = lane >> 4;

  __shared__ __align__(16) char smem[57344];
  u16* plu = (u16*)(smem + 49152 + w * 2048);  // [16 q][64 e], row 128B

  const char* KeB = (const char*)Ke + (size_t)bh * 524288;  // 1024*256*2
  const char* VtB = (const char*)Vt + (size_t)bh * 262144;  // 128*1024*2

  // Q fragments: wave w covers q rows qt*64 + w*16 + laneM
  const size_t qbase = ((size_t)bh * 1024 + qt * 64 + w * 16 + laneM) * 256 + laneG * 8;
  f32x4 qf[8];
  #pragma unroll
  for (int kk = 0; kk < 8; kk++) qf[kk] = *(const f32x4*)&Qe[qbase + kk * 32];

  float m_i[4], l_i[4];
  #pragma unroll
  for (int i = 0; i < 4; i++) { m_i[i] = -1e30f; l_i[i] = 0.f; }
  f32x4 accO[8];
  #pragma unroll
  for (int n = 0; n < 8; n++) accO[n] = (f32x4){0.f, 0.f, 0.f, 0.f};

  u16x8 kreg[4], vreg[2];
  auto loadRegs = [&](int ktn) {
    const char* ks = KeB + (size_t)ktn * 16384;  // 32 rows * 512B, linear
    #pragma unroll
    for (int j = 0; j < 4; j++) {
      int p = j * 4096 + tid * 16;
      kreg[j] = *(const u16x8*)(ks + p);
    }
    const char* vs = VtB + (size_t)ktn * 64;     // col chunk; row stride 2048B
    #pragma unroll
    for (int j = 0; j < 2; j++) {
      int p = j * 4096 + tid * 16;
      int r = p >> 6, x = p & 63;
      vreg[j] = *(const u16x8*)(vs + (size_t)r * 2048 + x);
    }
  };
  auto writeLDS = [&](int bsel) {
    char* kd = smem + (bsel ? 16384 : 0);
    #pragma unroll
    for (int j = 0; j < 4; j++) {
      int p = j * 4096 + tid * 16;
      int r = p >> 9, x = p & 511;
      *(u16x8*)(kd + r * 512 + (x ^ ((r & 7) << 4))) = kreg[j];
    }
    char* vd = smem + 32768 + (bsel ? 8192 : 0);
    #pragma unroll
    for (int j = 0; j < 2; j++) {
      int p = j * 4096 + tid * 16;
      int r = p >> 6, x = p & 63;
      *(u16x8*)(vd + r * 64 + (x ^ (((r >> 1) & 3) << 4))) = vreg[j];
    }
  };

  loadRegs(0);
  writeLDS(0);
  int cur = 0;
  const float scale = 0.08838834764831845f;  // 1/sqrt(128)

  for (int kt = 0; kt < 32; kt++) {
    if (kt < 31) loadRegs(kt + 1);  // hide HBM latency under barrier+compute
    __syncthreads();                // buf[cur] writes visible; prev readers done
    const char* Kc = smem + (cur ? 16384 : 0);
    const char* Vc = smem + 32768 + (cur ? 8192 : 0);

    // ---- QK^T: mfma(Q, K) -> S[q rows, kv lanes]  (R1 operand order) ----
    f32x4 accS[2];
    #pragma unroll
    for (int n = 0; n < 2; n++) accS[n] = (f32x4){0.f, 0.f, 0.f, 0.f};
    #pragma unroll
    for (int n = 0; n < 2; n++) {
      int r = n * 16 + laneM;
      const char* krow = Kc + r * 512;
      int sw = (r & 7) << 4;
      #pragma unroll
      for (int kk = 0; kk < 8; kk++) {
        f32x4 kf = *(const f32x4*)(krow + ((kk * 64 + laneG * 16) ^ sw));
        mfma_bf16_16x16x32(accS[n], qf[kk], kf);
      }
    }

    // ---- online softmax (R1 pattern): row i = laneG*4+i, kv = n*16+laneM --
    float p[2][4], sf[4];
    #pragma unroll
    for (int i = 0; i < 4; i++) {
      float mx = fmaxf(accS[0][i], accS[1][i]) * scale;
      #pragma unroll
      for (int m = 1; m < 16; m <<= 1) mx = fmaxf(mx, __shfl_xor(mx, m));
      float mnew = fmaxf(m_i[i], mx);
      sf[i] = __expf(m_i[i] - mnew);
      m_i[i] = mnew;
      float p0 = __expf(accS[0][i] * scale - mnew);
      float p1 = __expf(accS[1][i] * scale - mnew);
      p[0][i] = p0; p[1][i] = p1;
      float rs = p0 + p1;
      #pragma unroll
      for (int m = 1; m < 16; m <<= 1) rs += __shfl_xor(rs, m);
      l_i[i] = l_i[i] * sf[i] + rs;
    }
    #pragma unroll
    for (int n = 0; n < 8; n++) {
      accO[n][0] *= sf[0]; accO[n][1] *= sf[1];
      accO[n][2] *= sf[2]; accO[n][3] *= sf[3];
    }

    // ---- P -> LDS (R1 swizzle), read back as A-fragment ----
    #pragma unroll
    for (int n = 0; n < 2; n++)
      #pragma unroll
      for (int i = 0; i < 4; i++) {
        int row = laneG * 4 + i;
        int col = n * 16 + laneM;
        plu[row * 64 + (col ^ (((row >> 2) & 3) << 4))] = f2bf(p[n][i]);
      }
    f32x4 pa = *(const f32x4*)&plu[laneM * 64 +
                                   ((laneG * 8) ^ (((laneM >> 2) & 3) << 4))];

    // ---- PV: mfma(P, V^T-frag), kv=32 in one MFMA ----
    #pragma unroll
    for (int n = 0; n < 8; n++) {
      int r = n * 16 + laneM;
      f32x4 vf = *(const f32x4*)(Vc + r * 64 + ((laneG * 16) ^ (((r >> 1) & 3) << 4)));
      mfma_bf16_16x16x32(accO[n], pa, vf);
    }

    if (kt < 31) writeLDS(cur ^ 1);
    cur ^= 1;
  }

  // ---- epilogue (R1 verbatim) ----
  #pragma unroll
  for (int i = 0; i < 4; i++) {
    float inv_l = 1.f / l_i[i];
    int row = b * 1024 + qt * 64 + w * 16 + laneG * 4 + i;
    #pragma unroll
    for (int n = 0; n < 8; n++) {
      float o = accO[n][i] * inv_l;
      o = o + 0.05f * o * o;  // gate collapses (out2==out1); HAD term
      AO[(size_t)row * 2048 + h * 128 + n * 16 + laneM] = f2bf(o);
    }
  }
}

// ---------------- launch ----------------
extern "C" void kernel_launch(void* const* d_in, const int* in_sizes, int n_in,
                              void* d_out, int out_size, void* d_ws, size_t ws_size,
                              hipStream_t stream) {
  const float* x   = (const float*)d_in[0];
  const float* n1w = (const float*)d_in[1];
  const float* n2w = (const float*)d_in[2];
  const float* wq  = (const float*)d_in[3];
  const float* wk  = (const float*)d_in[4];
  const float* wv  = (const float*)d_in[5];
  const float* wo  = (const float*)d_in[6];
  const float* w1  = (const float*)d_in[8];
  const float* w3  = (const float*)d_in[9];
  const float* w2  = (const float*)d_in[10];

  char* ws = (char*)d_ws;
  u16* WQb = (u16*)(ws + 0);
  u16* WKb = (u16*)(ws + 8388608);
  u16* WVb = (u16*)(ws + 16777216);
  u16* WOb = (u16*)(ws + 25165824);
  u16* W1b = (u16*)(ws + 33554432);
  u16* W3b = (u16*)(ws + 67108864);
  u16* W2b = (u16*)(ws + 100663296);
  u16* XN  = (u16*)(ws + 134217728);
  float* QF = (float*)(ws + 142606336);
  float* KF = (float*)(ws + 159383552);
  float* VF = (float*)(ws + 176160768);
  u16* G1  = (u16*)(ws + 142606336);   // reuse QF/KF after qkv_post
  u16* QE  = (u16*)(ws + 192937984);
  u16* KE  = (u16*)(ws + 209715200);
  u16* U   = (u16*)(ws + 192937984);   // reuse QE/KE after attention
  u16* VT  = (u16*)(ws + 226492416);
  u16* AO  = (u16*)(ws + 234881024);
  float* H = (float*)(ws + 243269632);

  cvt_k<<<2048, 256, 0, stream>>>(wq, WQb, 524288);
  cvt_k<<<2048, 256, 0, stream>>>(wk, WKb, 524288);
  cvt_k<<<2048, 256, 0, stream>>>(wv, WVb, 524288);
  cvt_k<<<2048, 256, 0, stream>>>(wo, WOb, 524288);
  cvt_k<<<8192, 256, 0, stream>>>(w1, W1b, 2097152);
  cvt_k<<<8192, 256, 0, stream>>>(w3, W3b, 2097152);
  cvt_k<<<8192, 256, 0, stream>>>(w2, W2b, 2097152);

  rmsnorm_k<<<2048, 256, 0, stream>>>(x, n1w, XN);

  gemm_bt<EPI_F32><<<dim3(16, 16), 256, 0, stream>>>(XN, WQb, QF, nullptr, nullptr, nullptr, 2048, 2048, 2048);
  gemm_bt<EPI_F32><<<dim3(16, 16), 256, 0, stream>>>(XN, WKb, KF, nullptr, nullptr, nullptr, 2048, 2048, 2048);
  gemm_bt<EPI_F32><<<dim3(16, 16), 256, 0, stream>>>(XN, WVb, VF, nullptr, nullptr, nullptr, 2048, 2048, 2048);

  qkv_post_k<<<dim3(16, 32), 256, 0, stream>>>(QF, KF, VF, QE, KE, VT);

  attn_k<<<dim3(32, 16), 256, 0, stream>>>(QE, KE, VT, AO);

  gemm_bt<EPI_ADDF32><<<dim3(16, 16), 256, 0, stream>>>(AO, WOb, H, nullptr, x, nullptr, 2048, 2048, 2048);

  rmsnorm_k<<<2048, 256, 0, stream>>>(H, n2w, XN);

  gemm_bt<EPI_BF16><<<dim3(64, 16), 256, 0, stream>>>(XN, W1b, nullptr, G1, nullptr, nullptr, 2048, 8192, 2048);
  gemm_bt<EPI_SILUMUL><<<dim3(64, 16), 256, 0, stream>>>(XN, W3b, nullptr, U, nullptr, G1, 2048, 8192, 2048);
  gemm_bt<EPI_ADDF32><<<dim3(16, 16), 256, 0, stream>>>(U, W2b, (float*)d_out, nullptr, H, nullptr, 2048, 2048, 8192);
}

// Round 6
// 565.908 us; speedup vs baseline: 1.5423x; 1.2905x over previous
//
#include <hip/hip_runtime.h>
#include <hip/hip_bf16.h>

typedef unsigned short u16;
typedef unsigned int u32;
typedef u16 u16x8 __attribute__((ext_vector_type(8)));
typedef float f32x4 __attribute__((ext_vector_type(4)));

__device__ __forceinline__ u16 f2bf(float f) {
  union { float f; u32 u; } v; v.f = f;
  u32 r = v.u + 0x7FFFu + ((v.u >> 16) & 1u);
  return (u16)(r >> 16);
}
__device__ __forceinline__ float bf2f(u16 h) {
  union { u32 u; float f; } v; v.u = ((u32)h) << 16;
  return v.f;
}
__device__ __forceinline__ void mfma_bf16_16x16x32(f32x4& acc, const f32x4& a, const f32x4& b) {
  asm("v_mfma_f32_16x16x32_bf16 %0, %1, %2, %0" : "+v"(acc) : "v"(a), "v"(b));
}
__device__ __forceinline__ void gload_lds16(const void* g, void* l) {
  __builtin_amdgcn_global_load_lds(
      (const __attribute__((address_space(1))) unsigned int*)g,
      (__attribute__((address_space(3))) unsigned int*)l, 16, 0, 0);
}

// ---------------- fp32 -> bf16 weight convert ----------------
__global__ __launch_bounds__(256) void cvt_k(const float* __restrict__ src,
                                             u16* __restrict__ dst, int n8) {
  int i = blockIdx.x * 256 + threadIdx.x;
  if (i >= n8) return;
  float4 f0 = *(const float4*)&src[(size_t)i * 8];
  float4 f1 = *(const float4*)&src[(size_t)i * 8 + 4];
  u16x8 o;
  o[0] = f2bf(f0.x); o[1] = f2bf(f0.y); o[2] = f2bf(f0.z); o[3] = f2bf(f0.w);
  o[4] = f2bf(f1.x); o[5] = f2bf(f1.y); o[6] = f2bf(f1.z); o[7] = f2bf(f1.w);
  *(u16x8*)&dst[(size_t)i * 8] = o;
}

// cvt w1/w3 with 16-row group interleave: src row j -> dst row 32*(j/16)+(j%16)+half*16
__global__ __launch_bounds__(256) void cvt13_k(const float* __restrict__ src,
                                               u16* __restrict__ dst, int half) {
  int r = blockIdx.x;
  int dr = ((r >> 4) << 5) + (r & 15) + (half << 4);
  int t = threadIdx.x;
  const float* s = src + (size_t)r * 2048 + t * 8;
  float4 f0 = *(const float4*)s;
  float4 f1 = *(const float4*)(s + 4);
  u16x8 o;
  o[0] = f2bf(f0.x); o[1] = f2bf(f0.y); o[2] = f2bf(f0.z); o[3] = f2bf(f0.w);
  o[4] = f2bf(f1.x); o[5] = f2bf(f1.y); o[6] = f2bf(f1.z); o[7] = f2bf(f1.w);
  *(u16x8*)&dst[(size_t)dr * 2048 + t * 8] = o;
}

// ---------------- RMSNorm (fp32 in, bf16 out) ----------------
__global__ __launch_bounds__(256) void rmsnorm_k(const float* __restrict__ X,
                                                 const float* __restrict__ W,
                                                 u16* __restrict__ O) {
  const int row = blockIdx.x;
  const int tid = threadIdx.x;
  const float* x = X + (size_t)row * 2048;
  float4 v0 = *(const float4*)&x[tid * 8];
  float4 v1 = *(const float4*)&x[tid * 8 + 4];
  float s = v0.x * v0.x + v0.y * v0.y + v0.z * v0.z + v0.w * v0.w
          + v1.x * v1.x + v1.y * v1.y + v1.z * v1.z + v1.w * v1.w;
  #pragma unroll
  for (int m = 1; m < 64; m <<= 1) s += __shfl_xor(s, m);
  __shared__ float red[4];
  if ((tid & 63) == 0) red[tid >> 6] = s;
  __syncthreads();
  float tot = red[0] + red[1] + red[2] + red[3];
  float r = rsqrtf(tot * (1.0f / 2048.0f) + 1e-6f);
  float4 w0 = *(const float4*)&W[tid * 8];
  float4 w1 = *(const float4*)&W[tid * 8 + 4];
  u16x8 o;
  o[0] = f2bf(v0.x * r * w0.x); o[1] = f2bf(v0.y * r * w0.y);
  o[2] = f2bf(v0.z * r * w0.z); o[3] = f2bf(v0.w * r * w0.w);
  o[4] = f2bf(v1.x * r * w1.x); o[5] = f2bf(v1.y * r * w1.y);
  o[6] = f2bf(v1.z * r * w1.z); o[7] = f2bf(v1.w * r * w1.w);
  *(u16x8*)&O[(size_t)row * 2048 + tid * 8] = o;
}

// ---------------- GEMM: C[M,N] = A[M,K] * B[N,K]^T  (bf16 in, epilogues) ---
// 128x128 tile, BK=32, global_load_lds staging.  lda/ldb decoupled from K so
// split-K slices work.  blockIdx.z = split-K slice (A,B col offset z*Kt,
// Cf += z*M*N).
#define EPI_F32 0
#define EPI_ADDF32 1
#define EPI_SWIGLU 2

template <int EPI>
__global__ __launch_bounds__(256) void gemm_bt(const u16* __restrict__ A,
                                               const u16* __restrict__ B,
                                               float* __restrict__ Cf,
                                               u16* __restrict__ Cb,
                                               const float* __restrict__ R,
                                               int M, int N, int Kt,
                                               int lda, int ldb) {
  __shared__ __align__(16) u16 As[128 * 32];
  __shared__ __align__(16) u16 Bs[128 * 32];
  const int tid = threadIdx.x;
  const int lane = tid & 63;
  const int w = tid >> 6;
  const int wm = w >> 1, wn = w & 1;
  const int m0 = blockIdx.y * 128, n0 = blockIdx.x * 128;
  const int z = blockIdx.z;
  A += (size_t)z * Kt;
  B += (size_t)z * Kt;
  Cf += (size_t)z * M * N;
  const int r0 = tid >> 2;
  const int c0 = (tid & 3) * 8;
  const int r1 = r0 + 64;
  const int laneM = lane & 15;
  const int laneK = (lane >> 4) * 8;

  f32x4 acc[4][4];
  #pragma unroll
  for (int i = 0; i < 4; i++)
    #pragma unroll
    for (int j = 0; j < 4; j++) acc[i][j] = (f32x4){0.f, 0.f, 0.f, 0.f};

  const u16* Ar0 = &A[(size_t)(m0 + r0) * lda + c0];
  const u16* Ar1 = &A[(size_t)(m0 + r1) * lda + c0];
  const u16* Br0 = &B[(size_t)(n0 + r0) * ldb + c0];
  const u16* Br1 = &B[(size_t)(n0 + r1) * ldb + c0];
  u16* lA0 = &As[r0 * 32 + c0];
  u16* lA1 = &As[r1 * 32 + c0];
  u16* lB0 = &Bs[r0 * 32 + c0];
  u16* lB1 = &Bs[r1 * 32 + c0];

  for (int kt = 0; kt < Kt; kt += 32) {
    __syncthreads();
    gload_lds16(Ar0 + kt, lA0);
    gload_lds16(Ar1 + kt, lA1);
    gload_lds16(Br0 + kt, lB0);
    gload_lds16(Br1 + kt, lB1);
    __syncthreads();
    f32x4 af[4], bfr[4];
    #pragma unroll
    for (int mi = 0; mi < 4; mi++)
      af[mi] = *(const f32x4*)&As[(wm * 64 + mi * 16 + laneM) * 32 + laneK];
    #pragma unroll
    for (int ni = 0; ni < 4; ni++)
      bfr[ni] = *(const f32x4*)&Bs[(wn * 64 + ni * 16 + laneM) * 32 + laneK];
    #pragma unroll
    for (int mi = 0; mi < 4; mi++)
      #pragma unroll
      for (int ni = 0; ni < 4; ni++)
        mfma_bf16_16x16x32(acc[mi][ni], af[mi], bfr[ni]);
  }

  const int rowb = (lane >> 4) * 4;
  const int coll = lane & 15;
  #pragma unroll
  for (int mi = 0; mi < 4; mi++) {
    #pragma unroll
    for (int i = 0; i < 4; i++) {
      int row = m0 + wm * 64 + mi * 16 + rowb + i;
      if constexpr (EPI == EPI_SWIGLU) {
        // paired cols: ni even = w1 (gate), ni odd = w3 (value); out stride N/2
        #pragma unroll
        for (int ni = 0; ni < 4; ni += 2) {
          float g = acc[mi][ni][i];
          float u = acc[mi][ni + 1][i];
          float sg = g / (1.0f + __expf(-g));
          int j = (n0 >> 1) + wn * 32 + (ni >> 1) * 16 + coll;
          Cb[(size_t)row * (N >> 1) + j] = f2bf(sg * u);
        }
      } else {
        #pragma unroll
        for (int ni = 0; ni < 4; ni++) {
          int col = n0 + wn * 64 + ni * 16 + coll;
          size_t idx = (size_t)row * N + col;
          float v = acc[mi][ni][i];
          if constexpr (EPI == EPI_F32) Cf[idx] = v;
          else Cf[idx] = v + R[idx];
        }
      }
    }
  }
}

// ---------------- split-K reduce: out = P0+P1+P2+P3 + H ----------------
__global__ __launch_bounds__(256) void reduce5_k(const float* __restrict__ P,
                                                 const float* __restrict__ H,
                                                 float* __restrict__ out) {
  size_t i = ((size_t)blockIdx.x * 256 + threadIdx.x) * 4;
  const size_t MN = 4194304;
  float4 a = *(const float4*)&P[i];
  float4 b = *(const float4*)&P[MN + i];
  float4 c = *(const float4*)&P[2 * MN + i];
  float4 d = *(const float4*)&P[3 * MN + i];
  float4 h = *(const float4*)&H[i];
  float4 o;
  o.x = a.x + b.x + c.x + d.x + h.x;
  o.y = a.y + b.y + c.y + d.y + h.y;
  o.z = a.z + b.z + c.z + d.z + h.z;
  o.w = a.w + b.w + c.w + d.w + h.w;
  *(float4*)&out[i] = o;
}

// ---------------- RoPE + Qe/Ke build + V transpose ----------------
__device__ __forceinline__ void rope_row(const float* __restrict__ src,
                                         u16* __restrict__ dst, int s, int q4) {
  float vv[32];
  #pragma unroll
  for (int t = 0; t < 8; t++) {
    float4 f = *(const float4*)&src[t * 4];
    vv[t * 4] = f.x; vv[t * 4 + 1] = f.y; vv[t * 4 + 2] = f.z; vv[t * 4 + 3] = f.w;
  }
  u16 o1[32], o2[32];
  #pragma unroll
  for (int jl = 0; jl < 16; jl++) {
    int j = q4 * 16 + jl;
    float inv = exp2f(-(float)j * 0.20762050593046014f); // log2(10000)/64
    float ang = (float)s * inv;
    float sn, cs;
    __sincosf(ang, &sn, &cs);
    float a = vv[2 * jl], b = vv[2 * jl + 1];
    float r1 = a * cs - b * sn;
    float r2 = a * sn + b * cs;
    o1[2 * jl] = f2bf(r1);
    o1[2 * jl + 1] = f2bf(r2);
    o2[2 * jl] = f2bf(0.31622776601683794f * r1 * r1);  // sqrt(LAM)*x^2
    o2[2 * jl + 1] = f2bf(0.31622776601683794f * r2 * r2);
  }
  #pragma unroll
  for (int t = 0; t < 4; t++) {
    *(u16x8*)&dst[q4 * 32 + t * 8] = *(const u16x8*)&o1[t * 8];
    *(u16x8*)&dst[128 + q4 * 32 + t * 8] = *(const u16x8*)&o2[t * 8];
  }
}

__global__ __launch_bounds__(256) void qkv_post_k(const float* __restrict__ QKVF,
                                                  u16* __restrict__ Qe,
                                                  u16* __restrict__ Ke,
                                                  u16* __restrict__ Vt) {
  const int st = blockIdx.x;  // 0..15
  const int bh = blockIdx.y;  // 0..31
  const int b = bh >> 4, h = bh & 15;
  const int tid = threadIdx.x;
  {
    int r = tid >> 2, q4 = tid & 3;
    int s = st * 64 + r;
    size_t rowin = ((size_t)b * 1024 + s) * 6144 + h * 128 + q4 * 32;
    size_t rowe = ((size_t)bh * 1024 + s) * 256;
    rope_row(QKVF + rowin, Qe + rowe, s, q4);
    rope_row(QKVF + rowin + 2048, Ke + rowe, s, q4);
  }
  __shared__ __align__(16) u16 vts[128 * 72];
  {
    int r = tid >> 2, q4 = tid & 3;
    int s = st * 64 + r;
    const float* src = QKVF + ((size_t)b * 1024 + s) * 6144 + 4096 + h * 128 + q4 * 32;
    #pragma unroll
    for (int k = 0; k < 32; k += 4) {
      float4 f = *(const float4*)&src[k];
      int d = q4 * 32 + k;
      vts[(d + 0) * 72 + r] = f2bf(f.x);
      vts[(d + 1) * 72 + r] = f2bf(f.y);
      vts[(d + 2) * 72 + r] = f2bf(f.z);
      vts[(d + 3) * 72 + r] = f2bf(f.w);
    }
  }
  __syncthreads();
  {
    int d = tid >> 1, sp = (tid & 1) * 32;
    u16* dst = Vt + ((size_t)bh * 128 + d) * 1024 + st * 64 + sp;
    #pragma unroll
    for (int k = 0; k < 32; k += 8)
      *(u16x8*)&dst[k] = *(const u16x8*)&vts[d * 72 + sp + k];
  }
}

// ---------------- Flash attention (R5, unchanged) ----------------
__global__ __launch_bounds__(256, 2) void attn_k(const u16* __restrict__ Qe,
                                                 const u16* __restrict__ Ke,
                                                 const u16* __restrict__ Vt,
                                                 u16* __restrict__ AO) {
  const int bh = blockIdx.x;  // 0..31
  const int qt = blockIdx.y;  // 0..15
  const int b = bh >> 4, h = bh & 15;
  const int tid = threadIdx.x;
  const int w = tid >> 6, lane = tid & 63;
  const int laneM = lane & 15, laneG = lane >> 4;

  __shared__ __align__(16) char smem[57344];
  u16* plu = (u16*)(smem + 49152 + w * 2048);

  const char* KeB = (const char*)Ke + (size_t)bh * 524288;
  const char* VtB = (const char*)Vt + (size_t)bh * 262144;

  const size_t qbase = ((size_t)bh * 1024 + qt * 64 + w * 16 + laneM) * 256 + laneG * 8;
  f32x4 qf[8];
  #pragma unroll
  for (int kk = 0; kk < 8; kk++) qf[kk] = *(const f32x4*)&Qe[qbase + kk * 32];

  float m_i[4], l_i[4];
  #pragma unroll
  for (int i = 0; i < 4; i++) { m_i[i] = -1e30f; l_i[i] = 0.f; }
  f32x4 accO[8];
  #pragma unroll
  for (int n = 0; n < 8; n++) accO[n] = (f32x4){0.f, 0.f, 0.f, 0.f};

  u16x8 kreg[4], vreg[2];
  auto loadRegs = [&](int ktn) {
    const char* ks = KeB + (size_t)ktn * 16384;
    #pragma unroll
    for (int j = 0; j < 4; j++) {
      int p = j * 4096 + tid * 16;
      kreg[j] = *(const u16x8*)(ks + p);
    }
    const char* vs = VtB + (size_t)ktn * 64;
    #pragma unroll
    for (int j = 0; j < 2; j++) {
      int p = j * 4096 + tid * 16;
      int r = p >> 6, x = p & 63;
      vreg[j] = *(const u16x8*)(vs + (size_t)r * 2048 + x);
    }
  };
  auto writeLDS = [&](int bsel) {
    char* kd = smem + (bsel ? 16384 : 0);
    #pragma unroll
    for (int j = 0; j < 4; j++) {
      int p = j * 4096 + tid * 16;
      int r = p >> 9, x = p & 511;
      *(u16x8*)(kd + r * 512 + (x ^ ((r & 7) << 4))) = kreg[j];
    }
    char* vd = smem + 32768 + (bsel ? 8192 : 0);
    #pragma unroll
    for (int j = 0; j < 2; j++) {
      int p = j * 4096 + tid * 16;
      int r = p >> 6, x = p & 63;
      *(u16x8*)(vd + r * 64 + (x ^ (((r >> 1) & 3) << 4))) = vreg[j];
    }
  };

  loadRegs(0);
  writeLDS(0);
  int cur = 0;
  const float scale = 0.08838834764831845f;

  for (int kt = 0; kt < 32; kt++) {
    if (kt < 31) loadRegs(kt + 1);
    __syncthreads();
    const char* Kc = smem + (cur ? 16384 : 0);
    const char* Vc = smem + 32768 + (cur ? 8192 : 0);

    f32x4 accS[2];
    #pragma unroll
    for (int n = 0; n < 2; n++) accS[n] = (f32x4){0.f, 0.f, 0.f, 0.f};
    #pragma unroll
    for (int n = 0; n < 2; n++) {
      int r = n * 16 + laneM;
      const char* krow = Kc + r * 512;
      int sw = (r & 7) << 4;
      #pragma unroll
      for (int kk = 0; kk < 8; kk++) {
        f32x4 kf = *(const f32x4*)(krow + ((kk * 64 + laneG * 16) ^ sw));
        mfma_bf16_16x16x32(accS[n], qf[kk], kf);
      }
    }

    float p[2][4], sf[4];
    #pragma unroll
    for (int i = 0; i < 4; i++) {
      float mx = fmaxf(accS[0][i], accS[1][i]) * scale;
      #pragma unroll
      for (int m = 1; m < 16; m <<= 1) mx = fmaxf(mx, __shfl_xor(mx, m));
      float mnew = fmaxf(m_i[i], mx);
      sf[i] = __expf(m_i[i] - mnew);
      m_i[i] = mnew;
      float p0 = __expf(accS[0][i] * scale - mnew);
      float p1 = __expf(accS[1][i] * scale - mnew);
      p[0][i] = p0; p[1][i] = p1;
      float rs = p0 + p1;
      #pragma unroll
      for (int m = 1; m < 16; m <<= 1) rs += __shfl_xor(rs, m);
      l_i[i] = l_i[i] * sf[i] + rs;
    }
    #pragma unroll
    for (int n = 0; n < 8; n++) {
      accO[n][0] *= sf[0]; accO[n][1] *= sf[1];
      accO[n][2] *= sf[2]; accO[n][3] *= sf[3];
    }

    #pragma unroll
    for (int n = 0; n < 2; n++)
      #pragma unroll
      for (int i = 0; i < 4; i++) {
        int row = laneG * 4 + i;
        int col = n * 16 + laneM;
        plu[row * 64 + (col ^ (((row >> 2) & 3) << 4))] = f2bf(p[n][i]);
      }
    f32x4 pa = *(const f32x4*)&plu[laneM * 64 +
                                   ((laneG * 8) ^ (((laneM >> 2) & 3) << 4))];

    #pragma unroll
    for (int n = 0; n < 8; n++) {
      int r = n * 16 + laneM;
      f32x4 vf = *(const f32x4*)(Vc + r * 64 + ((laneG * 16) ^ (((r >> 1) & 3) << 4)));
      mfma_bf16_16x16x32(accO[n], pa, vf);
    }

    if (kt < 31) writeLDS(cur ^ 1);
    cur ^= 1;
  }

  #pragma unroll
  for (int i = 0; i < 4; i++) {
    float inv_l = 1.f / l_i[i];
    int row = b * 1024 + qt * 64 + w * 16 + laneG * 4 + i;
    #pragma unroll
    for (int n = 0; n < 8; n++) {
      float o = accO[n][i] * inv_l;
      o = o + 0.05f * o * o;  // gate collapses (out2==out1); HAD term
      AO[(size_t)row * 2048 + h * 128 + n * 16 + laneM] = f2bf(o);
    }
  }
}

// ---------------- launch ----------------
extern "C" void kernel_launch(void* const* d_in, const int* in_sizes, int n_in,
                              void* d_out, int out_size, void* d_ws, size_t ws_size,
                              hipStream_t stream) {
  const float* x   = (const float*)d_in[0];
  const float* n1w = (const float*)d_in[1];
  const float* n2w = (const float*)d_in[2];
  const float* wq  = (const float*)d_in[3];
  const float* wk  = (const float*)d_in[4];
  const float* wv  = (const float*)d_in[5];
  const float* wo  = (const float*)d_in[6];
  const float* w1  = (const float*)d_in[8];
  const float* w3  = (const float*)d_in[9];
  const float* w2  = (const float*)d_in[10];

  char* ws = (char*)d_ws;
  u16* WQKVb = (u16*)(ws + 0);          // [6144][2048] bf16, 25.2 MB
  u16* WOb   = (u16*)(ws + 25165824);   // 8.4 MB
  u16* W13b  = (u16*)(ws + 33554432);   // [16384][2048] interleaved, 67 MB
  u16* W2b   = (u16*)(ws + 100663296);  // [2048][8192], 33.6 MB
  u16* XN    = (u16*)(ws + 134217728);  // 8.4 MB (reused for HN)
  float* QKVF = (float*)(ws + 142606336); // [2048][6144] f32, 50.3 MB
  u16* U     = (u16*)(ws + 142606336);  // [2048][8192] bf16 (reuses QKVF after qkv_post)
  float* P   = (float*)(ws + 176160768); // 4x [2048][2048] f32 = 67 MB (over dead QKVF-tail/QE/KE/VT/AO)
  u16* QE    = (u16*)(ws + 192937984);  // 16.8 MB
  u16* KE    = (u16*)(ws + 209715200);  // 16.8 MB
  u16* VT    = (u16*)(ws + 226492416);  // 8.4 MB
  u16* AO    = (u16*)(ws + 234881024);  // 8.4 MB
  float* H   = (float*)(ws + 243269632); // 16.8 MB, ends 260046848

  // weight conversions
  cvt_k<<<2048, 256, 0, stream>>>(wq, WQKVb, 524288);
  cvt_k<<<2048, 256, 0, stream>>>(wk, WQKVb + 4194304, 524288);
  cvt_k<<<2048, 256, 0, stream>>>(wv, WQKVb + 8388608, 524288);
  cvt_k<<<2048, 256, 0, stream>>>(wo, WOb, 524288);
  cvt13_k<<<8192, 256, 0, stream>>>(w1, W13b, 0);
  cvt13_k<<<8192, 256, 0, stream>>>(w3, W13b, 1);
  cvt_k<<<8192, 256, 0, stream>>>(w2, W2b, 2097152);

  rmsnorm_k<<<2048, 256, 0, stream>>>(x, n1w, XN);

  // fused QKV: [2048,2048] x [6144,2048]^T -> QKVF f32
  gemm_bt<EPI_F32><<<dim3(48, 16), 256, 0, stream>>>(
      XN, WQKVb, QKVF, nullptr, nullptr, 2048, 6144, 2048, 2048, 2048);

  qkv_post_k<<<dim3(16, 32), 256, 0, stream>>>(QKVF, QE, KE, VT);

  attn_k<<<dim3(32, 16), 256, 0, stream>>>(QE, KE, VT, AO);

  // wo + residual -> H
  gemm_bt<EPI_ADDF32><<<dim3(16, 16), 256, 0, stream>>>(
      AO, WOb, H, nullptr, x, 2048, 2048, 2048, 2048, 2048);

  rmsnorm_k<<<2048, 256, 0, stream>>>(H, n2w, XN);

  // fused w1|w3 interleaved + swiglu epilogue -> U bf16 [2048][8192]
  gemm_bt<EPI_SWIGLU><<<dim3(128, 16), 256, 0, stream>>>(
      XN, W13b, nullptr, U, nullptr, 2048, 16384, 2048, 2048, 2048);

  // w2 split-K=4 -> partials P[z]
  gemm_bt<EPI_F32><<<dim3(16, 16, 4), 256, 0, stream>>>(
      U, W2b, P, nullptr, nullptr, 2048, 2048, 2048, 8192, 8192);

  // out = sum(P) + H
  reduce5_k<<<4096, 256, 0, stream>>>(P, H, (float*)d_out);
}